// Round 4
// baseline (596.968 us; speedup 1.0000x reference)
//
#include <hip/hip_runtime.h>
#include <hip/hip_bf16.h>
#include <stdint.h>

#define TSTEPS 4

typedef __bf16 bf16_t;
typedef __attribute__((ext_vector_type(8))) __bf16 bf16x8;
typedef __attribute__((ext_vector_type(16))) float f32x16;

typedef const __attribute__((address_space(1))) void* gas_ptr;
typedef __attribute__((address_space(3))) void* las_ptr;

__device__ __forceinline__ void glds16(const void* g, void* l) {
    // 16B per lane, LDS dest = wave-uniform base + lane*16
    __builtin_amdgcn_global_load_lds((gas_ptr)g, (las_ptr)l, 16, 0, 0);
}

// ---------------------------------------------------------------------------
// Stage 1: input LIF encoder (elementwise). XLA-exact rounding.
// ---------------------------------------------------------------------------
__global__ void spike_encode_kernel(const float* __restrict__ x,
                                    unsigned short* __restrict__ s1, int n)
{
    int i = blockIdx.x * blockDim.x + threadIdx.x;
    if (i >= n) return;
    float xv = x[i];
    float v = 0.0f;
#pragma unroll
    for (int t = 0; t < TSTEPS; ++t) {
        v = __fadd_rn(v, __fmul_rn(__fsub_rn(xv, v), 0.5f));
        bool sp = (v >= 1.0f);
        s1[(size_t)t * n + i] = sp ? 0x3F80 : 0;   // bf16 1.0 / 0.0
        v = sp ? 0.0f : v;
    }
}

// ---------------------------------------------------------------------------
// Weight prep: W [K][N] fp32 -> hiT, loT [N][K] bf16 (2-term split, transposed
// so B-fragments read contiguous k). Tiled transpose via LDS.
// ---------------------------------------------------------------------------
__global__ void split_transpose_kernel(const float* __restrict__ W,
                                       bf16_t* __restrict__ hiT,
                                       bf16_t* __restrict__ loT,
                                       int K, int N)
{
    __shared__ float tile[32][33];
    int k0 = blockIdx.x * 32, n0 = blockIdx.y * 32;
    int tx = threadIdx.x & 31, ty = threadIdx.x >> 5;  // 8 rows per pass
    for (int kk = ty; kk < 32; kk += 8)
        tile[kk][tx] = W[(size_t)(k0 + kk) * N + n0 + tx];
    __syncthreads();
    for (int nn = ty; nn < 32; nn += 8) {
        float w = tile[tx][nn];                 // = W[k0+tx][n0+nn]
        bf16_t h = (bf16_t)w;
        bf16_t l = (bf16_t)(w - (float)h);
        size_t o = (size_t)(n0 + nn) * K + (k0 + tx);
        hiT[o] = h;
        loT[o] = l;
    }
}

// ---------------------------------------------------------------------------
// Fused MFMA GEMM + multistep LIF.  R4: 32x32x16 MFMA + LDS double-buffer.
// A: spikes [T][M][K] bf16 (0/1 exact). WhiT/WloT: [N][K] bf16 split weights.
// Block: 128x128 tile, 4 waves of 64x64 (2x2 tiles of 32x32 per wave).
// K-loop: stage(k+1) -> compute(k) -> one __syncthreads per iter; the barrier
// drain waits on loads issued a full compute phase earlier (latency hidden).
//
// LDS swizzle (unchanged from R3): 16B chunk at slot s of row r holds global
// k-quad kq = (s - r - (r>>2)) & 3; staging dest stays lane-linear for
// global_load_lds; frag reads use p(c,r) = (c + r + (r>>2)) & 3.
// ---------------------------------------------------------------------------
template <int K, bool LAST>
__global__ __launch_bounds__(256, 2)
void gemm_lif_mfma(const unsigned short* __restrict__ A,
                   const bf16_t* __restrict__ WhiT,
                   const bf16_t* __restrict__ WloT,
                   const float* __restrict__ bias,
                   unsigned short* __restrict__ Sout,
                   float* __restrict__ Out,
                   int M, int N)
{
    constexpr int BK = 32;
    constexpr int NK = K / BK;
    __shared__ bf16_t As[2][128 * BK];   // 2 x 8 KB
    __shared__ bf16_t Bh[2][128 * BK];
    __shared__ bf16_t Bl[2][128 * BK];

    const int tid = threadIdx.x;
    const int lane = tid & 63;
    const int wid = tid >> 6;
    const int l31 = lane & 31;
    const int half = lane >> 5;
    const int wave_m = (wid & 1) * 64;
    const int wave_n = (wid >> 1) * 64;
    const int m0 = blockIdx.x * 128;
    const int n0 = blockIdx.y * 128;

    // --- staging descriptors: 512 chunks of 16B per tile, 2 rounds/thread ---
    const int i0 = wid * 64 + lane;
    const int i1 = i0 + 256;
    const int r0 = i0 >> 2, r1 = i1 >> 2;
    const int kq0 = ((i0 & 3) - r0 - (r0 >> 2)) & 3;
    const int kq1 = ((i1 & 3) - r1 - (r1 >> 2)) & 3;

    const int ldsOff0 = (wid * 64) * 8;          // bf16 elements; +lane*16B implicit
    const int ldsOff1 = (256 + wid * 64) * 8;

    const size_t srcA0 = (size_t)(m0 + r0) * K * 2 + (size_t)kq0 * 16;
    const size_t srcA1 = (size_t)(m0 + r1) * K * 2 + (size_t)kq1 * 16;
    const char* pBh0 = (const char*)WhiT + (size_t)(n0 + r0) * K * 2 + kq0 * 16;
    const char* pBh1 = (const char*)WhiT + (size_t)(n0 + r1) * K * 2 + kq1 * 16;
    const char* pBl0 = (const char*)WloT + (size_t)(n0 + r0) * K * 2 + kq0 * 16;
    const char* pBl1 = (const char*)WloT + (size_t)(n0 + r1) * K * 2 + kq1 * 16;

    // --- fragment LDS byte offsets: [mt|nt][kstep] ---
    int offA[2][2], offB[2][2];
#pragma unroll
    for (int mt = 0; mt < 2; ++mt)
#pragma unroll
        for (int ks = 0; ks < 2; ++ks) {
            int row = wave_m + mt * 32 + l31;
            int c = ks * 2 + half;
            offA[mt][ks] = row * 64 + (((c + row + (row >> 2)) & 3) << 4);
            row = wave_n + mt * 32 + l31;
            offB[mt][ks] = row * 64 + (((c + row + (row >> 2)) & 3) << 4);
        }

    float biasv[2];
#pragma unroll
    for (int nt = 0; nt < 2; ++nt)
        biasv[nt] = bias[n0 + wave_n + nt * 32 + l31];

    f32x16 v[2][2];
    uint64_t bits[2][2];
#pragma unroll
    for (int mt = 0; mt < 2; ++mt)
#pragma unroll
        for (int nt = 0; nt < 2; ++nt) {
            for (int r = 0; r < 16; ++r) v[mt][nt][r] = 0.0f;
            bits[mt][nt] = 0ull;
        }

    for (int t = 0; t < TSTEPS; ++t) {
        const char* At = (const char*)A + (size_t)t * M * K * 2;
        f32x16 acc[2][2];
#pragma unroll
        for (int mt = 0; mt < 2; ++mt)
#pragma unroll
            for (int nt = 0; nt < 2; ++nt)
                for (int r = 0; r < 16; ++r) acc[mt][nt][r] = 0.0f;

        // prologue: stage k-chunk 0 into buffer 0
        {
            glds16(At + srcA0, &As[0][ldsOff0]);
            glds16(At + srcA1, &As[0][ldsOff1]);
            glds16(pBh0, &Bh[0][ldsOff0]);
            glds16(pBh1, &Bh[0][ldsOff1]);
            glds16(pBl0, &Bl[0][ldsOff0]);
            glds16(pBl1, &Bl[0][ldsOff1]);
        }
        __syncthreads();

        for (int kk = 0; kk < NK; ++kk) {
            // stage next chunk into the other buffer (async, drains at barrier)
            if (kk + 1 < NK) {
                const int nb = (kk + 1) & 1;
                const size_t kb = (size_t)(kk + 1) * BK * 2;
                glds16(At + srcA0 + kb, &As[nb][ldsOff0]);
                glds16(At + srcA1 + kb, &As[nb][ldsOff1]);
                glds16(pBh0 + kb, &Bh[nb][ldsOff0]);
                glds16(pBh1 + kb, &Bh[nb][ldsOff1]);
                glds16(pBl0 + kb, &Bl[nb][ldsOff0]);
                glds16(pBl1 + kb, &Bl[nb][ldsOff1]);
            }

            const int b = kk & 1;
            bf16x8 af[2][2], fh[2][2], fl[2][2];
#pragma unroll
            for (int mt = 0; mt < 2; ++mt)
#pragma unroll
                for (int ks = 0; ks < 2; ++ks)
                    af[mt][ks] = *(const bf16x8*)((const char*)&As[b][0] + offA[mt][ks]);
#pragma unroll
            for (int nt = 0; nt < 2; ++nt)
#pragma unroll
                for (int ks = 0; ks < 2; ++ks) {
                    fh[nt][ks] = *(const bf16x8*)((const char*)&Bh[b][0] + offB[nt][ks]);
                    fl[nt][ks] = *(const bf16x8*)((const char*)&Bl[b][0] + offB[nt][ks]);
                }
#pragma unroll
            for (int ks = 0; ks < 2; ++ks)
#pragma unroll
                for (int mt = 0; mt < 2; ++mt)
#pragma unroll
                    for (int nt = 0; nt < 2; ++nt) {
                        acc[mt][nt] = __builtin_amdgcn_mfma_f32_32x32x16_bf16(
                            af[mt][ks], fh[nt][ks], acc[mt][nt], 0, 0, 0);
                        acc[mt][nt] = __builtin_amdgcn_mfma_f32_32x32x16_bf16(
                            af[mt][ks], fl[nt][ks], acc[mt][nt], 0, 0, 0);
                    }
            __syncthreads();   // joins waves; drains this iter's stage + reads
        }

        // --- LIF epilogue for timestep t (XLA-exact scan arithmetic) ---
#pragma unroll
        for (int mt = 0; mt < 2; ++mt)
#pragma unroll
            for (int nt = 0; nt < 2; ++nt)
#pragma unroll
                for (int r = 0; r < 16; ++r) {
                    float y = __fadd_rn(acc[mt][nt][r], biasv[nt]);
                    float vv = v[mt][nt][r];
                    vv = __fadd_rn(vv, __fmul_rn(__fsub_rn(y, vv), 0.5f));
                    bool sp = (vv >= 1.0f);
                    v[mt][nt][r] = sp ? 0.0f : vv;
                    if (LAST) {
                        bits[mt][nt] |= sp ? (1ull << (r * 4 + t)) : 0ull;
                    } else {
                        int row = (r & 3) + 8 * (r >> 2) + 4 * half;
                        int m = m0 + wave_m + mt * 32 + row;
                        int n = n0 + wave_n + nt * 32 + l31;
                        Sout[(size_t)t * M * N + (size_t)m * N + n] =
                            sp ? 0x3F80 : 0;
                    }
                }
    }

    if (LAST) {
#pragma unroll
        for (int mt = 0; mt < 2; ++mt)
#pragma unroll
            for (int nt = 0; nt < 2; ++nt)
#pragma unroll
                for (int r = 0; r < 16; ++r) {
                    int row = (r & 3) + 8 * (r >> 2) + 4 * half;
                    int m = m0 + wave_m + mt * 32 + row;
                    int n = n0 + wave_n + nt * 32 + l31;
                    int cnt = __popc((unsigned)((bits[mt][nt] >> (r * 4)) & 0xFull));
                    Out[(size_t)m * N + n] = 0.25f * (float)cnt;
                }
    }
}

// ---------------------------------------------------------------------------
// out2[b][d] = mean over L of out[b][l][d]. Exact in fp32 (quarter-integers).
// ---------------------------------------------------------------------------
__global__ void mean_over_L_kernel(const float* __restrict__ out,
                                   float* __restrict__ out2,
                                   int B, int L, int D)
{
    int id = blockIdx.x * blockDim.x + threadIdx.x;
    if (id >= B * D) return;
    int b = id / D, d = id - b * D;
    const float* p = out + (size_t)b * L * D + d;
    float s = 0.0f;
    for (int l = 0; l < L; ++l) s += p[(size_t)l * D];
    out2[id] = s * (1.0f / (float)L);
}

// ---------------------------------------------------------------------------
extern "C" void kernel_launch(void* const* d_in, const int* in_sizes, int n_in,
                              void* d_out, int out_size, void* d_ws, size_t ws_size,
                              hipStream_t stream)
{
    const float* inputs  = (const float*)d_in[0];  // [16,512,128]
    const float* enc_W   = (const float*)d_in[1];  // [128,1024]
    const float* enc_b   = (const float*)d_in[2];  // [1024]
    const float* W_cells = (const float*)d_in[3];  // [2,1024,1024]
    const float* b_cells = (const float*)d_in[4];  // [2,1024]

    const int B = 16, L = 512, C = 128, D = 1024;
    const int M = B * L;  // 8192

    // ws layout: s1 8MB | W1h/l 0.5MB | W2h/l 4MB | W3h/l 4MB | h0 64MB | h1 64MB
    char* ws = (char*)d_ws;
    size_t off = 0;
    unsigned short* s1 = (unsigned short*)(ws + off); off += (size_t)TSTEPS * M * C * 2;
    bf16_t* W1h = (bf16_t*)(ws + off); off += (size_t)C * D * 2;
    bf16_t* W1l = (bf16_t*)(ws + off); off += (size_t)C * D * 2;
    bf16_t* W2h = (bf16_t*)(ws + off); off += (size_t)D * D * 2;
    bf16_t* W2l = (bf16_t*)(ws + off); off += (size_t)D * D * 2;
    bf16_t* W3h = (bf16_t*)(ws + off); off += (size_t)D * D * 2;
    bf16_t* W3l = (bf16_t*)(ws + off); off += (size_t)D * D * 2;
    unsigned short* h0 = (unsigned short*)(ws + off); off += (size_t)TSTEPS * M * D * 2;
    unsigned short* h1 = (unsigned short*)(ws + off);

    float* out  = (float*)d_out;          // [M, D]
    float* out2 = out + (size_t)M * D;    // [B, D]

    split_transpose_kernel<<<dim3(C / 32, D / 32), 256, 0, stream>>>(
        enc_W, W1h, W1l, C, D);
    split_transpose_kernel<<<dim3(D / 32, D / 32), 256, 0, stream>>>(
        W_cells, W2h, W2l, D, D);
    split_transpose_kernel<<<dim3(D / 32, D / 32), 256, 0, stream>>>(
        W_cells + (size_t)D * D, W3h, W3l, D, D);

    const int n1 = M * C;
    spike_encode_kernel<<<(n1 + 255) / 256, 256, 0, stream>>>(inputs, s1, n1);

    dim3 grid(M / 128, D / 128);
    gemm_lif_mfma<128, false><<<grid, 256, 0, stream>>>(
        s1, W1h, W1l, enc_b, h0, nullptr, M, D);
    gemm_lif_mfma<1024, false><<<grid, 256, 0, stream>>>(
        h0, W2h, W2l, b_cells, h1, nullptr, M, D);
    gemm_lif_mfma<1024, true><<<grid, 256, 0, stream>>>(
        h1, W3h, W3l, b_cells + D, nullptr, out, M, D);

    mean_over_L_kernel<<<(B * D + 255) / 256, 256, 0, stream>>>(
        out, out2, B, L, D);
}